// Round 14
// baseline (50.036 us; speedup 1.0000x reference)
//
#include <hip/hip_runtime.h>

#define H_    1024
#define B_    512
#define OUT_  512

typedef _Float16 half8 __attribute__((ext_vector_type(8)));
typedef _Float16 half4 __attribute__((ext_vector_type(4)));
typedef float    f32x4 __attribute__((ext_vector_type(4)));

__device__ __forceinline__ half8 cvt8(float4 lo, float4 hi) {
    half8 h;
    h[0] = (_Float16)lo.x; h[1] = (_Float16)lo.y; h[2] = (_Float16)lo.z; h[3] = (_Float16)lo.w;
    h[4] = (_Float16)hi.x; h[5] = (_Float16)hi.y; h[6] = (_Float16)hi.z; h[7] = (_Float16)hi.w;
    return h;
}

// Workgroup barrier WITHOUT the vmcnt(0) drain __syncthreads() emits.
__device__ __forceinline__ void barrier_nodrain() {
    asm volatile("s_waitcnt lgkmcnt(0)" ::: "memory");
    __builtin_amdgcn_s_barrier();
}

// ===========================================================================
// Dispatch 1, 384 blocks:
//  d < 128:  kv block. 64 batches x 64 j-cols, FULL K (16 steps, BK=64),
//            dual-B (Wk,Wv) sharing one staged x-tile. k,v stay f32; LDS
//            epilogue reduces to power sums momp[jn][b][16]:
//            m_n = sum_j s^n, Mv_n = sum_j s^n (v+bv), s = k/32.
//            k,v never touch global memory. jn==0 blocks also init out=bo.
//  d >= 128: q block (R12-proven 64x64, kz x2, 8 steps) -> qph f16 partials.
// ===========================================================================
__global__ __launch_bounds__(256) void fused1_kernel(const float* __restrict__ x,
                                                     const float* __restrict__ Wq,
                                                     const float* __restrict__ Wk,
                                                     const float* __restrict__ Wv,
                                                     const float* __restrict__ bv,
                                                     const float* __restrict__ bo,
                                                     _Float16* __restrict__ qph,
                                                     float* __restrict__ momp,
                                                     float* __restrict__ outp)
{
    __shared__ __align__(16) char smem[49152];

    const int tid  = threadIdx.x;
    const int lane = tid & 63;
    const int w    = tid >> 6;
    const int d    = blockIdx.x;

    if (d < 128) {
        // ================= kv block =================
        _Float16* sA  = (_Float16*)smem;               // [2][64*64] = 16 KB
        _Float16* sBk = (_Float16*)(smem + 16384);     // [2][64*64] = 16 KB
        _Float16* sBv = (_Float16*)(smem + 32768);     // [2][64*64] = 16 KB

        const int wr = w >> 1, wc = w & 1;
        const int fr = lane & 15, fg = lane >> 4;

        const int xcd = d & 7;
        const int r   = d >> 3;                // 0..15
        const int jn  = xcd * 2 + (r >> 3);    // j-tile 0..15 (64 j each)
        const int bm  = (r & 7) * 64;          // batch base

        // bo-init (8 blocks: jn==0): out rows bm..bm+63 = bo
        if (jn == 0) {
            const int rr  = tid >> 2;
            const int seg = tid & 3;
            float4* orow = (float4*)(outp + (size_t)(bm + rr) * OUT_);
#pragma unroll
            for (int qq = 0; qq < 32; ++qq)
                orow[seg * 32 + qq] = ((const float4*)bo)[seg * 32 + qq];
        }

        // --- A staging (x tile, same as R12) ---
        const int srow = tid >> 2;
        const int cq   = tid & 3;
        const float* Ap = x + (size_t)(bm + srow) * H_ + cq * 16;
        const int g0 = srow * 64 + (((2 * cq)     ^ (srow & 7)) << 3);
        const int g1 = srow * 64 + (((2 * cq + 1) ^ (srow & 7)) << 3);

        // --- B staging: threads 0-127 -> Wk, 128-255 -> Wv; 32 f32 each ---
        const int half_ = tid >> 7;
        const int srB   = (tid & 127) >> 1;    // 0..63
        const int cqB   = tid & 1;             // granule group 0-3 / 4-7
        const float* Wkv = half_ ? Wv : Wk;
        const float* Bp  = Wkv + (size_t)(jn * 64 + srB) * H_ + cqB * 32;
        _Float16* sBm = half_ ? sBv : sBk;
        int gB[4];
#pragma unroll
        for (int jj = 0; jj < 4; ++jj)
            gB[jj] = srB * 64 + (((4 * cqB + jj) ^ (srB & 7)) << 3);

        f32x4 acck[2][2] = {}, accv[2][2] = {};

        float4 a0 = *(const float4*)(Ap + 0), a1 = *(const float4*)(Ap + 4);
        float4 a2 = *(const float4*)(Ap + 8), a3 = *(const float4*)(Ap + 12);
        float4 b[8];
#pragma unroll
        for (int q = 0; q < 8; ++q) b[q] = *(const float4*)(Bp + q * 4);

        for (int t = 0; t < 16; ++t) {
            const int buf = (t & 1) << 12;     // halves
            half8 hA0 = cvt8(a0, a1), hA1 = cvt8(a2, a3);
            half8 hB[4];
#pragma unroll
            for (int jj = 0; jj < 4; ++jj)
                hB[jj] = cvt8(b[2 * jj], b[2 * jj + 1]);
            if (t < 15) {
                const float* An = Ap + (t + 1) * 64;
                const float* Bn = Bp + (t + 1) * 64;
                a0 = *(const float4*)(An + 0); a1 = *(const float4*)(An + 4);
                a2 = *(const float4*)(An + 8); a3 = *(const float4*)(An + 12);
#pragma unroll
                for (int q = 0; q < 8; ++q) b[q] = *(const float4*)(Bn + q * 4);
            }
            *(half8*)&sA[buf + g0] = hA0;
            *(half8*)&sA[buf + g1] = hA1;
#pragma unroll
            for (int jj = 0; jj < 4; ++jj)
                *(half8*)&sBm[buf + gB[jj]] = hB[jj];
            barrier_nodrain();

#pragma unroll
            for (int kh = 0; kh < 2; ++kh) {
                const int p = (((kh * 4 + fg) ^ (fr & 7)) << 3);
                half8 af[2], bk[2], bb[2];
#pragma unroll
                for (int mi = 0; mi < 2; ++mi)
                    af[mi] = *(const half8*)&sA[buf + (wr * 32 + mi * 16 + fr) * 64 + p];
#pragma unroll
                for (int ni = 0; ni < 2; ++ni) {
                    const int rowb = (wc * 32 + ni * 16 + fr) * 64 + p;
                    bk[ni] = *(const half8*)&sBk[buf + rowb];
                    bb[ni] = *(const half8*)&sBv[buf + rowb];
                }
#pragma unroll
                for (int mi = 0; mi < 2; ++mi)
#pragma unroll
                    for (int ni = 0; ni < 2; ++ni) {
                        acck[mi][ni] = __builtin_amdgcn_mfma_f32_16x16x32_f16(
                                           af[mi], bk[ni], acck[mi][ni], 0, 0, 0);
                        accv[mi][ni] = __builtin_amdgcn_mfma_f32_16x16x32_f16(
                                           af[mi], bb[ni], accv[mi][ni], 0, 0, 0);
                    }
            }
        }

        // --- epilogue: dump k,v f32 to LDS, reduce to moment partials ---
        __syncthreads();
        float* kd = (float*)smem;              // [64][68] padded
        float* vd = kd + 64 * 68;              // [64][68]
#pragma unroll
        for (int mi = 0; mi < 2; ++mi) {
            const int row0 = wr * 32 + mi * 16 + fg * 4;
#pragma unroll
            for (int ni = 0; ni < 2; ++ni) {
                const int col = wc * 32 + ni * 16 + fr;
#pragma unroll
                for (int rr = 0; rr < 4; ++rr) {
                    kd[(row0 + rr) * 68 + col] = acck[mi][ni][rr];
                    vd[(row0 + rr) * 68 + col] = accv[mi][ni][rr];
                }
            }
        }
        __syncthreads();
        {
            const int b_  = tid >> 2;          // 0..63
            const int sub = tid & 3;
            const int j0  = sub * 16;
            float m[8] = {}, Mv[8] = {};
#pragma unroll
            for (int jj = 0; jj < 16; ++jj) {
                float s  = kd[b_ * 68 + j0 + jj] * (1.0f / 32.0f);
                float vv = vd[b_ * 68 + j0 + jj] + bv[jn * 64 + j0 + jj];
                float p  = 1.0f;
#pragma unroll
                for (int n = 0; n < 8; ++n) {
                    m[n] += p;
                    Mv[n] = fmaf(p, vv, Mv[n]);
                    p *= s;
                }
            }
#pragma unroll
            for (int off = 1; off <= 2; off <<= 1)
#pragma unroll
                for (int n = 0; n < 8; ++n) {
                    m[n]  += __shfl_xor(m[n],  off, 64);
                    Mv[n] += __shfl_xor(Mv[n], off, 64);
                }
            if (sub == 0) {
                float* mout = momp + ((size_t)jn * B_ + bm + b_) * 16;
                f32x4 v0 = {m[0], m[1], m[2], m[3]};
                f32x4 v1 = {m[4], m[5], m[6], m[7]};
                f32x4 v2 = {Mv[0], Mv[1], Mv[2], Mv[3]};
                f32x4 v3 = {Mv[4], Mv[5], Mv[6], Mv[7]};
                ((f32x4*)mout)[0] = v0; ((f32x4*)mout)[1] = v1;
                ((f32x4*)mout)[2] = v2; ((f32x4*)mout)[3] = v3;
            }
        }
    } else {
        // ================= q block (R12-proven) =================
        _Float16* sA = (_Float16*)smem;            // [2][64*64]
        _Float16* sB = (_Float16*)(smem + 16384);  // [2][64*64]

        const int wr = w >> 1, wc = w & 1;
        const int fr = lane & 15, fg = lane >> 4;

        const int id  = d - 128;               // 0..255
        const int xcd = id & 7;
        const int jj  = id >> 3;               // 0..31
        const int bm  = (jj & 7) * 64;
        const int t2  = jj >> 3;               // 0..3
        const int kz  = t2 & 1;
        const int bn  = (xcd * 2 + (t2 >> 1)) * 64;   // 0..960
        const int k0  = kz * 512;

        const int srow = tid >> 2;
        const int cq   = tid & 3;
        const float* Ap = x  + (size_t)(bm + srow) * H_ + k0 + cq * 16;
        const float* Bp = Wq + (size_t)(bn + srow) * H_ + k0 + cq * 16;

        const int g0    = (((2 * cq)     ^ (srow & 7)) << 3);
        const int g1    = (((2 * cq + 1) ^ (srow & 7)) << 3);
        const int wbase = srow * 64;

        f32x4 acc[2][2] = {};

        float4 a0 = *(const float4*)(Ap + 0), a1 = *(const float4*)(Ap + 4);
        float4 a2 = *(const float4*)(Ap + 8), a3 = *(const float4*)(Ap + 12);
        float4 b0 = *(const float4*)(Bp + 0), b1 = *(const float4*)(Bp + 4);
        float4 b2 = *(const float4*)(Bp + 8), b3 = *(const float4*)(Bp + 12);

        for (int t = 0; t < 8; ++t) {
            const int buf = (t & 1) << 12;
            half8 hA0 = cvt8(a0, a1), hA1 = cvt8(a2, a3);
            half8 hB0 = cvt8(b0, b1), hB1 = cvt8(b2, b3);
            if (t < 7) {
                const float* An = Ap + (t + 1) * 64;
                const float* Bn = Bp + (t + 1) * 64;
                a0 = *(const float4*)(An + 0); a1 = *(const float4*)(An + 4);
                a2 = *(const float4*)(An + 8); a3 = *(const float4*)(An + 12);
                b0 = *(const float4*)(Bn + 0); b1 = *(const float4*)(Bn + 4);
                b2 = *(const float4*)(Bn + 8); b3 = *(const float4*)(Bn + 12);
            }
            *(half8*)&sA[buf + wbase + g0] = hA0;
            *(half8*)&sA[buf + wbase + g1] = hA1;
            *(half8*)&sB[buf + wbase + g0] = hB0;
            *(half8*)&sB[buf + wbase + g1] = hB1;
            barrier_nodrain();

#pragma unroll
            for (int kh = 0; kh < 2; ++kh) {
                const int p = (((kh * 4 + fg) ^ (fr & 7)) << 3);
                half8 af[2], bf[2];
#pragma unroll
                for (int mi = 0; mi < 2; ++mi)
                    af[mi] = *(const half8*)&sA[buf + (wr * 32 + mi * 16 + fr) * 64 + p];
#pragma unroll
                for (int ni = 0; ni < 2; ++ni)
                    bf[ni] = *(const half8*)&sB[buf + (wc * 32 + ni * 16 + fr) * 64 + p];
#pragma unroll
                for (int mi = 0; mi < 2; ++mi)
#pragma unroll
                    for (int ni = 0; ni < 2; ++ni)
                        acc[mi][ni] = __builtin_amdgcn_mfma_f32_16x16x32_f16(
                                          af[mi], bf[ni], acc[mi][ni], 0, 0, 0);
            }
        }

        _Float16* Cb = qph + (size_t)kz * B_ * H_ + (size_t)bm * H_ + bn;
#pragma unroll
        for (int mi = 0; mi < 2; ++mi) {
            const int r0 = wr * 32 + mi * 16 + fg * 4;
#pragma unroll
            for (int ni = 0; ni < 2; ++ni) {
                const int col = wc * 32 + ni * 16 + fr;
#pragma unroll
                for (int rr = 0; rr < 4; ++rr)
                    Cb[(size_t)(r0 + rr) * H_ + col] = (_Float16)acc[mi][ni][rr];
            }
        }
    }
}

// ===========================================================================
// Dispatch 2: eval. Per batch: sum 16 j-tile moment partials, apply 1/n!,
// Horner on c = q (2 f16 kz-partials summed) -> attnh f16.
// ===========================================================================
__global__ __launch_bounds__(256) void eval_kernel(const _Float16* __restrict__ qph,
                                                   const float* __restrict__ momp,
                                                   _Float16* __restrict__ attnh)
{
    __shared__ float red2[16][17];
    __shared__ float sm[16];
    const int b   = blockIdx.x;
    const int tid = threadIdx.x;

    {
        const int n = tid >> 4;       // moment index 0..15
        const int p = tid & 15;       // j-tile 0..15
        red2[n][p] = momp[((size_t)p * B_ + b) * 16 + n];
    }
    __syncthreads();
    if (tid < 16) {
        const float invfact[8] = {1.f, 1.f, 0.5f, 1.f/6.f, 1.f/24.f,
                                  1.f/120.f, 1.f/720.f, 1.f/5040.f};
        float s = 0.0f;
#pragma unroll
        for (int p = 0; p < 16; ++p) s += red2[tid][p];
        sm[tid] = s * invfact[tid & 7];
    }
    __syncthreads();

    half4 qa = ((const half4*)(qph + (size_t)b * H_))[tid];
    half4 qb = ((const half4*)(qph + (size_t)(B_ + b) * H_))[tid];
    half4 o;
#pragma unroll
    for (int e = 0; e < 4; ++e) {
        float c = (float)qa[e] + (float)qb[e];
        float den = sm[7];
#pragma unroll
        for (int n = 6; n >= 0; --n) den = fmaf(den, c, sm[n]);
        float num = sm[15];
#pragma unroll
        for (int n = 14; n >= 8; --n) num = fmaf(num, c, sm[n]);
        o[e] = (_Float16)(num / den);
    }
    ((half4*)attnh)[b * 256 + tid] = o;
}

// ===========================================================================
// Dispatch 3 (R12-proven): out += attn @ Wo^T, bias pre-initialized.
// BM=BN=32, K-split x2 -> 512 blocks, 8 steps, f32 atomicAdd (2 adds/elem).
// ===========================================================================
__global__ __launch_bounds__(256) void out_kernel(const _Float16* __restrict__ attnh,
                                                  const float* __restrict__ Wo,
                                                  float* __restrict__ outp)
{
    __shared__ __align__(16) _Float16 sA[2][32 * 64];
    __shared__ __align__(16) _Float16 sB[2][32 * 64];

    const int tid  = threadIdx.x;
    const int lane = tid & 63;
    const int w    = tid >> 6;
    const int wr   = w >> 1, wc = w & 1;
    const int fr   = lane & 15, fg = lane >> 4;

    const int d   = blockIdx.x;
    const int xcd = d & 7;
    const int j   = d >> 3;                  // 0..63
    const int kz  = xcd & 1;
    const int bm  = (j & 15) * 32;
    const int bn  = ((xcd >> 1) * 4 + (j >> 4)) * 32;   // 0..480
    const int k0  = kz * 512;

    const int srow = tid >> 3;
    const int cg_  = tid & 7;
    const _Float16* Ap = attnh + (size_t)(bm + srow) * H_ + k0 + cg_ * 8;
    const float*    Bp = Wo    + (size_t)(bn + srow) * H_ + k0 + cg_ * 8;

    const int sw    = (cg_ ^ (srow & 7)) << 3;
    const int wbase = srow * 64;

    f32x4 acc = {};

    half8  a0 = *(const half8*)Ap;
    float4 b0 = *(const float4*)(Bp + 0), b1 = *(const float4*)(Bp + 4);

    for (int t = 0; t < 8; ++t) {
        const int buf = t & 1;
        half8 hA = a0;
        half8 hB = cvt8(b0, b1);
        if (t < 7) {
            a0 = *(const half8*)(Ap + (t + 1) * 64);
            b0 = *(const float4*)(Bp + (t + 1) * 64);
            b1 = *(const float4*)(Bp + (t + 1) * 64 + 4);
        }
        *(half8*)&sA[buf][wbase + sw] = hA;
        *(half8*)&sB[buf][wbase + sw] = hB;
        barrier_nodrain();

#pragma unroll
        for (int kh = 0; kh < 2; ++kh) {
            const int p = (((kh * 4 + fg) ^ (fr & 7)) << 3);
            half8 af = *(const half8*)&sA[buf][(wr * 16 + fr) * 64 + p];
            half8 bf = *(const half8*)&sB[buf][(wc * 16 + fr) * 64 + p];
            acc = __builtin_amdgcn_mfma_f32_16x16x32_f16(af, bf, acc, 0, 0, 0);
        }
    }

    const int row0 = bm + wr * 16 + fg * 4;
    const int col  = bn + wc * 16 + fr;
#pragma unroll
    for (int r = 0; r < 4; ++r)
        atomicAdd(&outp[(size_t)(row0 + r) * OUT_ + col], acc[r]);
}

extern "C" void kernel_launch(void* const* d_in, const int* in_sizes, int n_in,
                              void* d_out, int out_size, void* d_ws, size_t ws_size,
                              hipStream_t stream)
{
    const float* x  = (const float*)d_in[0];
    const float* Wq = (const float*)d_in[1];
    const float* Wk = (const float*)d_in[2];
    const float* Wv = (const float*)d_in[3];
    const float* bv = (const float*)d_in[4];
    const float* Wo = (const float*)d_in[5];
    const float* bo = (const float*)d_in[6];
    float* out = (float*)d_out;

    char* ws = (char*)d_ws;
    _Float16* qph   = (_Float16*)ws;                // [2][512][1024] f16 = 2 MB
    _Float16* attnh = (_Float16*)(ws + (2 << 20));  // [512][1024] f16 = 1 MB
    float*    momp  = (float*)   (ws + (3 << 20));  // [16][512][16] f32 = 0.5 MB

    fused1_kernel<<<dim3(384), 256, 0, stream>>>(x, Wq, Wk, Wv, bv, bo,
                                                 qph, momp, out);
    eval_kernel<<<dim3(B_), 256, 0, stream>>>(qph, momp, attnh);
    out_kernel<<<dim3(512), 256, 0, stream>>>(attnh, Wo, out);
}

// Round 15
// 30.238 us; speedup vs baseline: 1.6547x; 1.6547x over previous
//
#include <hip/hip_runtime.h>

#define H_    1024
#define B_    512
#define OUT_  512
#define SLAB_ ((size_t)B_ * 3072)   // halves per K-partial slab

typedef _Float16 half8 __attribute__((ext_vector_type(8)));
typedef _Float16 half4 __attribute__((ext_vector_type(4)));
typedef float    f32x4 __attribute__((ext_vector_type(4)));

__device__ __forceinline__ half8 cvt8(float4 lo, float4 hi) {
    half8 h;
    h[0] = (_Float16)lo.x; h[1] = (_Float16)lo.y; h[2] = (_Float16)lo.z; h[3] = (_Float16)lo.w;
    h[4] = (_Float16)hi.x; h[5] = (_Float16)hi.y; h[6] = (_Float16)hi.z; h[7] = (_Float16)hi.w;
    return h;
}

// Workgroup barrier WITHOUT the vmcnt(0) drain __syncthreads() emits.
__device__ __forceinline__ void barrier_nodrain() {
    asm volatile("s_waitcnt lgkmcnt(0)" ::: "memory");
    __builtin_amdgcn_s_barrier();
}

// ===========================================================================
// qkv (R12-proven): 64x64 tiles, BK=64, 8 K-steps, K-split x2, 4 waves
// (2x2, each 32x32), 768 blocks, XCD-chunked bm-fastest decode.
// Output: f16 partials qkvph[kz][B][3072]. K-loop fully unrolled (static
// buf/t, no tail branch -> compiler can pipeline across steps).
// ===========================================================================
__global__ __launch_bounds__(256) void qkv_kernel(const float* __restrict__ x,
                                                  const float* __restrict__ Wq,
                                                  const float* __restrict__ Wk,
                                                  const float* __restrict__ Wv,
                                                  _Float16* __restrict__ qkvph)
{
    __shared__ __align__(16) _Float16 sA[2][64 * 64];
    __shared__ __align__(16) _Float16 sB[2][64 * 64];

    const int tid  = threadIdx.x;
    const int lane = tid & 63;
    const int w    = tid >> 6;
    const int wr   = w >> 1, wc = w & 1;
    const int fr   = lane & 15, fg = lane >> 4;

    // XCD-chunked job swizzle (768 = 8 * 96, bijective), bm fastest
    const int d    = blockIdx.x;
    const int job  = (d & 7) * 96 + (d >> 3);
    const int bm   = (job & 7) * 64;
    const int rest = job >> 3;                 // 0..95
    const int kz   = (rest >= 48) ? 1 : 0;
    const int bn   = (rest - kz * 48) * 64;    // 0..3071
    const int k0   = kz * 512;

    const int wsel = bn >> 10;
    const float* W = (wsel == 0) ? Wq : (wsel == 1) ? Wk : Wv;
    const int brow = bn & 1023;

    const int srow = tid >> 2;
    const int cq   = tid & 3;
    const float* Ap = x + (size_t)(bm + srow) * H_ + k0 + cq * 16;
    const float* Bp = W + (size_t)(brow + srow) * H_ + k0 + cq * 16;

    const int g0    = (((2 * cq)     ^ (srow & 7)) << 3);
    const int g1    = (((2 * cq + 1) ^ (srow & 7)) << 3);
    const int wbase = srow * 64;

    f32x4 acc[2][2] = {};

    float4 a0 = *(const float4*)(Ap + 0), a1 = *(const float4*)(Ap + 4);
    float4 a2 = *(const float4*)(Ap + 8), a3 = *(const float4*)(Ap + 12);
    float4 b0 = *(const float4*)(Bp + 0), b1 = *(const float4*)(Bp + 4);
    float4 b2 = *(const float4*)(Bp + 8), b3 = *(const float4*)(Bp + 12);

#pragma unroll
    for (int t = 0; t < 8; ++t) {
        const int buf = t & 1;
        half8 hA0 = cvt8(a0, a1), hA1 = cvt8(a2, a3);
        half8 hB0 = cvt8(b0, b1), hB1 = cvt8(b2, b3);
        if (t < 7) {
            const float* An = Ap + (t + 1) * 64;
            const float* Bn = Bp + (t + 1) * 64;
            a0 = *(const float4*)(An + 0); a1 = *(const float4*)(An + 4);
            a2 = *(const float4*)(An + 8); a3 = *(const float4*)(An + 12);
            b0 = *(const float4*)(Bn + 0); b1 = *(const float4*)(Bn + 4);
            b2 = *(const float4*)(Bn + 8); b3 = *(const float4*)(Bn + 12);
        }
        *(half8*)&sA[buf][wbase + g0] = hA0;
        *(half8*)&sA[buf][wbase + g1] = hA1;
        *(half8*)&sB[buf][wbase + g0] = hB0;
        *(half8*)&sB[buf][wbase + g1] = hB1;
        barrier_nodrain();

#pragma unroll
        for (int kh = 0; kh < 2; ++kh) {
            const int p = (((kh * 4 + fg) ^ (fr & 7)) << 3);
            half8 af[2], bf[2];
#pragma unroll
            for (int mi = 0; mi < 2; ++mi)
                af[mi] = *(const half8*)&sA[buf][(wr * 32 + mi * 16 + fr) * 64 + p];
#pragma unroll
            for (int ni = 0; ni < 2; ++ni)
                bf[ni] = *(const half8*)&sB[buf][(wc * 32 + ni * 16 + fr) * 64 + p];
#pragma unroll
            for (int mi = 0; mi < 2; ++mi)
#pragma unroll
                for (int ni = 0; ni < 2; ++ni)
                    acc[mi][ni] = __builtin_amdgcn_mfma_f32_16x16x32_f16(
                                      af[mi], bf[ni], acc[mi][ni], 0, 0, 0);
        }
    }

    _Float16* Cb = qkvph + (size_t)kz * SLAB_ + (size_t)bm * 3072 + bn;
#pragma unroll
    for (int mi = 0; mi < 2; ++mi) {
        const int r0 = wr * 32 + mi * 16 + fg * 4;
#pragma unroll
        for (int ni = 0; ni < 2; ++ni) {
            const int col = wc * 32 + ni * 16 + fr;
#pragma unroll
            for (int r = 0; r < 4; ++r)
                Cb[(size_t)(r0 + r) * 3072 + col] = (_Float16)acc[mi][ni][r];
        }
    }
}

// ===========================================================================
// attn: Taylor moments (deg 7) + Horner eval from 2 f16 K-partials (+bv).
// ALSO initializes out-row b to bo (so out_kernel can pure-atomicAdd).
// ===========================================================================
__global__ __launch_bounds__(256) void attn_kernel(const _Float16* __restrict__ qkvph,
                                                   const float* __restrict__ bv,
                                                   const float* __restrict__ bo,
                                                   _Float16* __restrict__ attnh,
                                                   float* __restrict__ outp)
{
    __shared__ float red[4][16];
    __shared__ float sm[16];
    const int b   = blockIdx.x;
    const int tid = threadIdx.x;
    const _Float16* p0 = qkvph + (size_t)b * 3072;
    const _Float16* p1 = p0 + SLAB_;

    // init out row b = bo (128 float4 writes by threads 0..127)
    if (tid < 128)
        ((float4*)(outp + (size_t)b * OUT_))[tid] = ((const float4*)bo)[tid];

    half4 ka = ((const half4*)(p0 + 1024))[tid];
    half4 kb = ((const half4*)(p1 + 1024))[tid];
    half4 va = ((const half4*)(p0 + 2048))[tid];
    half4 vb = ((const half4*)(p1 + 2048))[tid];
    float4 bv4 = ((const float4*)bv)[tid];

    const float ks[4] = {(float)ka[0] + (float)kb[0], (float)ka[1] + (float)kb[1],
                         (float)ka[2] + (float)kb[2], (float)ka[3] + (float)kb[3]};
    const float vs[4] = {(float)va[0] + (float)vb[0] + bv4.x,
                         (float)va[1] + (float)vb[1] + bv4.y,
                         (float)va[2] + (float)vb[2] + bv4.z,
                         (float)va[3] + (float)vb[3] + bv4.w};

    float m[8] = {}, Mv[8] = {};
#pragma unroll
    for (int e = 0; e < 4; ++e) {
        float s = ks[e] * (1.0f / 32.0f);
        float v = vs[e];
        float p = 1.0f;
#pragma unroll
        for (int n = 0; n < 8; ++n) {
            m[n] += p;
            Mv[n] = fmaf(p, v, Mv[n]);
            p *= s;
        }
    }
#pragma unroll
    for (int off = 32; off; off >>= 1)
#pragma unroll
        for (int n = 0; n < 8; ++n) {
            m[n]  += __shfl_xor(m[n],  off, 64);
            Mv[n] += __shfl_xor(Mv[n], off, 64);
        }
    const int wave = tid >> 6;
    if ((tid & 63) == 0) {
#pragma unroll
        for (int n = 0; n < 8; ++n) {
            red[wave][n]     = m[n];
            red[wave][n + 8] = Mv[n];
        }
    }
    __syncthreads();
    if (tid < 16) {
        const float invfact[8] = {1.f, 1.f, 0.5f, 1.f/6.f, 1.f/24.f,
                                  1.f/120.f, 1.f/720.f, 1.f/5040.f};
        sm[tid] = (red[0][tid] + red[1][tid] + red[2][tid] + red[3][tid])
                  * invfact[tid & 7];
    }
    __syncthreads();

    half4 qa = ((const half4*)p0)[tid];
    half4 qb = ((const half4*)p1)[tid];
    half4 o;
#pragma unroll
    for (int e = 0; e < 4; ++e) {
        float c = (float)qa[e] + (float)qb[e];
        float den = sm[7];
#pragma unroll
        for (int n = 6; n >= 0; --n) den = fmaf(den, c, sm[n]);
        float num = sm[15];
#pragma unroll
        for (int n = 14; n >= 8; --n) num = fmaf(num, c, sm[n]);
        o[e] = (_Float16)(num / den);
    }
    ((half4*)attnh)[b * 256 + tid] = o;
}

// ===========================================================================
// out += attn @ Wo^T (bias pre-initialized by attn_kernel). BM=BN=32,
// K-split x2 -> 512 blocks (2/CU), 8 steps (unrolled), f32 atomicAdd
// epilogue (exactly 2 commutative adds per element -> deterministic).
// ===========================================================================
__global__ __launch_bounds__(256) void out_kernel(const _Float16* __restrict__ attnh,
                                                  const float* __restrict__ Wo,
                                                  float* __restrict__ outp)
{
    __shared__ __align__(16) _Float16 sA[2][32 * 64];
    __shared__ __align__(16) _Float16 sB[2][32 * 64];

    const int tid  = threadIdx.x;
    const int lane = tid & 63;
    const int w    = tid >> 6;
    const int wr   = w >> 1, wc = w & 1;
    const int fr   = lane & 15, fg = lane >> 4;

    // 512 = 8 xcd * 64 jobs; job = {16 bm (fast) x 4 bn}; kz = xcd&1
    const int d   = blockIdx.x;
    const int xcd = d & 7;
    const int j   = d >> 3;                  // 0..63
    const int kz  = xcd & 1;
    const int bm  = (j & 15) * 32;
    const int bn  = ((xcd >> 1) * 4 + (j >> 4)) * 32;   // 0..480
    const int k0  = kz * 512;

    const int srow = tid >> 3;
    const int cg_  = tid & 7;
    const _Float16* Ap = attnh + (size_t)(bm + srow) * H_ + k0 + cg_ * 8;
    const float*    Bp = Wo    + (size_t)(bn + srow) * H_ + k0 + cg_ * 8;

    const int sw    = (cg_ ^ (srow & 7)) << 3;
    const int wbase = srow * 64;

    f32x4 acc = {};

    half8  a0 = *(const half8*)Ap;
    float4 b0 = *(const float4*)(Bp + 0), b1 = *(const float4*)(Bp + 4);

#pragma unroll
    for (int t = 0; t < 8; ++t) {
        const int buf = t & 1;
        half8 hA = a0;
        half8 hB = cvt8(b0, b1);
        if (t < 7) {
            a0 = *(const half8*)(Ap + (t + 1) * 64);
            b0 = *(const float4*)(Bp + (t + 1) * 64);
            b1 = *(const float4*)(Bp + (t + 1) * 64 + 4);
        }
        *(half8*)&sA[buf][wbase + sw] = hA;
        *(half8*)&sB[buf][wbase + sw] = hB;
        barrier_nodrain();

#pragma unroll
        for (int kh = 0; kh < 2; ++kh) {
            const int p = (((kh * 4 + fg) ^ (fr & 7)) << 3);
            half8 af = *(const half8*)&sA[buf][(wr * 16 + fr) * 64 + p];
            half8 bf = *(const half8*)&sB[buf][(wc * 16 + fr) * 64 + p];
            acc = __builtin_amdgcn_mfma_f32_16x16x32_f16(af, bf, acc, 0, 0, 0);
        }
    }

    const int row0 = bm + wr * 16 + fg * 4;
    const int col  = bn + wc * 16 + fr;
#pragma unroll
    for (int r = 0; r < 4; ++r)
        atomicAdd(&outp[(size_t)(row0 + r) * OUT_ + col], acc[r]);
}

extern "C" void kernel_launch(void* const* d_in, const int* in_sizes, int n_in,
                              void* d_out, int out_size, void* d_ws, size_t ws_size,
                              hipStream_t stream)
{
    const float* x  = (const float*)d_in[0];
    const float* Wq = (const float*)d_in[1];
    const float* Wk = (const float*)d_in[2];
    const float* Wv = (const float*)d_in[3];
    const float* bv = (const float*)d_in[4];
    const float* Wo = (const float*)d_in[5];
    const float* bo = (const float*)d_in[6];
    float* out = (float*)d_out;

    char* ws = (char*)d_ws;
    _Float16* qkvph = (_Float16*)ws;                 // [2][512][3072] f16 = 6.3 MB
    _Float16* attnh = (_Float16*)(ws + (8 << 20));   // [512][1024] f16 = 1 MB

    qkv_kernel<<<dim3(768), 256, 0, stream>>>(x, Wq, Wk, Wv, qkvph);
    attn_kernel<<<dim3(B_), 256, 0, stream>>>(qkvph, bv, bo, attnh, out);
    out_kernel<<<dim3(512), 256, 0, stream>>>(attnh, Wo, out);
}